// Round 5
// baseline (45.193 us; speedup 1.0000x reference)
//
#include <hip/hip_runtime.h>

#define BB 1024
#define SS 256
#define VV 256
#define HH 10
#define GG 40   // 4*H
#define LL 15

__device__ __forceinline__ float fexp2(float x) {
#if __has_builtin(__builtin_amdgcn_exp2f)
    return __builtin_amdgcn_exp2f(x);
#else
    return exp2f(x);
#endif
}
__device__ __forceinline__ float frcp(float x) {
#if __has_builtin(__builtin_amdgcn_rcpf)
    return __builtin_amdgcn_rcpf(x);
#else
    return 1.0f / x;
#endif
}
__device__ __forceinline__ float rdlane_f(float v, int srcLane) {
#if __has_builtin(__builtin_amdgcn_readlane)
    return __int_as_float(__builtin_amdgcn_readlane(__float_as_int(v), srcLane));
#else
    return __shfl(v, srcLane, 64);
#endif
}
__device__ __forceinline__ int rdlane_i(int v, int srcLane) {
#if __has_builtin(__builtin_amdgcn_readlane)
    return __builtin_amdgcn_readlane(v, srcLane);
#else
    return __shfl(v, srcLane, 64);
#endif
}
template<int CTRL>
__device__ __forceinline__ float dpp_qbcast(float v) {
#if __has_builtin(__builtin_amdgcn_mov_dpp)
    return __int_as_float(__builtin_amdgcn_mov_dpp(__float_as_int(v), CTRL, 0xF, 0xF, true));
#else
    return __shfl(v, (threadIdx.x & 60) + (CTRL & 3), 64);
#endif
}

// One wave per batch element. Lane = 4*k + t; t in {0:i,1:f,2:g,3:o}.
// h is NEVER materialized on the critical chain: h_k = o_k*(2*r2_k-1), so
// next dot = seed + sum( (2*wh_k*o_k) * r2_k ) with coefficients c2_k and
// seed built off-chain (o arrives ~6 levels before r2). Cell state kept
// pre-scaled: cs2 = K2*c, so tanh(c)'s exp2 consumes cs2 directly; the
// g-gate's K2*tanh scaling is applied post-DPP with uniform constants.
// Critical chain per step (15 levels):
//   readlane(r2) -> dot(5) -> exp2 -> add -> rcp -> DPP -> p,q -> igs -> cs2
//   -> exp2 -> add -> rcp
__global__ __launch_bounds__(256, 1) void charrnn_lstm_kernel(
    const int*   __restrict__ x,     // [B,S]
    const float* __restrict__ Wx,    // [V,4H]
    const float* __restrict__ Wh,    // [H,4H]
    const float* __restrict__ bias,  // [4H]
    const float* __restrict__ Wd,    // [H,L]
    const float* __restrict__ bd,    // [L]
    const float* __restrict__ dropr, // [1]
    float*       __restrict__ out)   // [B,L]
{
    const int tid  = threadIdx.x;
    const int wave = tid >> 6;
    const int lane = tid & 63;
    const int batch = blockIdx.x * 4 + wave;

    int k = lane >> 2;               // hidden unit
    int t = lane & 3;                // gate type
    if (lane >= GG) { k = 0; t = 0; }  // idle lanes mirror; never sourced
    const int jg = t * HH + k;       // column in [i(10) f(10) g(10) o(10)]

    // x row into registers: xq0[lane]=x[lane]; xsh[r][lane]=x[min(64r+lane+6,255)]
    const int* xrow = x + (size_t)batch * SS;
    const int xq0 = xrow[lane];
    int xsh[4];
    #pragma unroll
    for (int r = 0; r < 4; ++r) {
        int p = 64 * r + lane + 6;
        xsh[r] = xrow[p > SS - 1 ? SS - 1 : p];
    }

    const float LOG2E = 1.4426950408889634f;
    const bool  isTanh = (t == 2);
    const float m  = isTanh ? (-2.0f * LOG2E) : (-LOG2E);   // preact slope
    const float K2   = -2.0f * LOG2E;                        // cell tanh slope
    const float K2x2 = 2.0f * K2;                            // uniform
    const float nK2  = -K2;                                  // uniform

    // wh2[k] = 2 * m * Wh[k][jg]  (coefficient basis; dotB = 0.5 * sum c2)
    float wh2[HH];
    #pragma unroll
    for (int kk = 0; kk < HH; ++kk) wh2[kk] = 2.0f * m * Wh[kk * GG + jg];
    const float bjm = bias[jg] * m;

    // 6-deep Wx pipeline prologue (folded: seed(s=0), w1m(1), w2m(2); raw 3..5)
    const int i0 = rdlane_i(xq0, 0);
    const int i1 = rdlane_i(xq0, 1);
    const int i2 = rdlane_i(xq0, 2);
    const int i3 = rdlane_i(xq0, 3);
    const int i4 = rdlane_i(xq0, 4);
    const int i5 = rdlane_i(xq0, 5);
    float seed = fmaf(Wx[i0 * GG + jg], m, bjm);   // h=0 at t=0 -> dot = seed
    float w1m  = fmaf(Wx[i1 * GG + jg], m, bjm);
    float w2m  = fmaf(Wx[i2 * GG + jg], m, bjm);
    float r3   = Wx[i3 * GG + jg];
    float r4   = Wx[i4 * GG + jg];
    float r5   = Wx[i5 * GG + jg];

    float c2[HH];                    // 2*wh*o coefficients (zero at t=0)
    #pragma unroll
    for (int kk = 0; kk < HH; ++kk) c2[kk] = 0.0f;
    float cs2 = 0.0f;                // K2 * c
    float r2  = 0.5f;                // sigma(2c) with c=0
    float rr  = 0.0f;                // last sigma register (o lives on 4k+3)

    #pragma unroll
    for (int r = 0; r < 4; ++r) {
        const int xs_r = xsh[r];
        #pragma unroll 8
        for (int i = 0; i < 64; ++i) {
            // ---- transport: r2_k from lane 4k (quad-redundant value) ----
            const float t0 = rdlane_f(r2, 0),  t1 = rdlane_f(r2, 4);
            const float t2 = rdlane_f(r2, 8),  t3 = rdlane_f(r2, 12);
            const float t4 = rdlane_f(r2, 16), t5 = rdlane_f(r2, 20);
            const float t6 = rdlane_f(r2, 24), t7 = rdlane_f(r2, 28);
            const float t8 = rdlane_f(r2, 32), t9 = rdlane_f(r2, 36);

            // ---- dot: gm = seed + sum c2_k * r2_k (3-way split, 5 levels) ----
            float gA = fmaf(c2[2], t2, fmaf(c2[1], t1, fmaf(c2[0], t0, seed)));
            float gB = fmaf(c2[5], t5, fmaf(c2[4], t4, c2[3] * t3));
            float gC = fmaf(c2[9], t9, fmaf(c2[8], t8, fmaf(c2[7], t7, c2[6] * t6)));
            const float gm = gC + (gA + gB);

            // ---- sigma-half: rr = rcp(1+exp2(gm)) (g-scale applied post-DPP) ----
            const float e = fexp2(gm);
            rr = frcp(1.0f + e);

            // ---- gather i,f,g via DPP quad broadcasts of raw rr ----
            const float iv  = dpp_qbcast<0x00>(rr);
            const float fv  = dpp_qbcast<0x55>(rr);
            const float gvr = dpp_qbcast<0xAA>(rr);

            // ---- cell: igs = iv * K2*tanh(g) = 2K2*(iv*gvr) - K2*iv ----
            const float p = iv * gvr;
            const float q = iv * nK2;
            const float igs = fmaf(p, K2x2, q);
            cs2 = fmaf(fv, cs2, igs);            // cs2 = K2*c
            const float e2 = fexp2(cs2);
            r2 = frcp(1.0f + e2);                // sigma(2c); tanh = 2*r2-1

            // ======== off-chain phase B (overlaps the chain) ========
            // o_k = rr on lane 4k+3; coefficients + seed for NEXT step
            const float o0 = rdlane_f(rr, 3),  o1 = rdlane_f(rr, 7);
            const float o2v = rdlane_f(rr, 11), o3 = rdlane_f(rr, 15);
            const float o4 = rdlane_f(rr, 19), o5 = rdlane_f(rr, 23);
            const float o6 = rdlane_f(rr, 27), o7 = rdlane_f(rr, 31);
            const float o8 = rdlane_f(rr, 35), o9 = rdlane_f(rr, 39);
            c2[0] = wh2[0] * o0;  c2[1] = wh2[1] * o1;
            c2[2] = wh2[2] * o2v; c2[3] = wh2[3] * o3;
            c2[4] = wh2[4] * o4;  c2[5] = wh2[5] * o5;
            c2[6] = wh2[6] * o6;  c2[7] = wh2[7] * o7;
            c2[8] = wh2[8] * o8;  c2[9] = wh2[9] * o9;
            const float T01 = c2[0] + c2[1], T23 = c2[2] + c2[3];
            const float T45 = c2[4] + c2[5], T67 = c2[6] + c2[7];
            const float T89 = c2[8] + c2[9];
            const float TA = T01 + T23, TB = T45 + T67;
            const float Tall = (TA + TB) + T89;
            seed = fmaf(-0.5f, Tall, w1m);       // w1m - sum(wh*o)

            // Wx prefetch for step s+6 (SGPR index -> SALU addr)
            const int idxn = rdlane_i(xs_r, i);
            const float rawNew = Wx[idxn * GG + jg];

            // rotate pipeline
            w1m = w2m;
            w2m = fmaf(r3, m, bjm);
            r3 = r4; r4 = r5; r5 = rawNew;
        }
    }

    // final h_k = o_k * (2*r2_k - 1) on lane 4k+3
    const float hv = fmaf(rr + rr, r2, -rr);
    float hs[HH];
    #pragma unroll
    for (int kk = 0; kk < HH; ++kk) hs[kk] = rdlane_f(hv, 4 * kk + 3);

    // dropout scale (rate=0 -> 1) + dense head on lanes < 15
    const float scale = 1.0f / (1.0f - dropr[0]);
    const int l = (lane < LL) ? lane : 0;
    float acc = bd[l];
    #pragma unroll
    for (int kk = 0; kk < HH; ++kk)
        acc = fmaf(hs[kk] * scale, Wd[kk * LL + l], acc);
    if (lane < LL) out[(size_t)batch * LL + lane] = acc;
}

extern "C" void kernel_launch(void* const* d_in, const int* in_sizes, int n_in,
                              void* d_out, int out_size, void* d_ws, size_t ws_size,
                              hipStream_t stream) {
    const int*   x     = (const int*)d_in[0];
    const float* Wx    = (const float*)d_in[1];
    const float* Wh    = (const float*)d_in[2];
    const float* b     = (const float*)d_in[3];
    const float* Wd    = (const float*)d_in[4];
    const float* bd    = (const float*)d_in[5];
    const float* dropr = (const float*)d_in[6];
    float* out = (float*)d_out;

    dim3 grid(BB / 4);   // 256 blocks x 4 waves = 1024 waves, 1/SIMD chip-wide
    dim3 block(256);
    charrnn_lstm_kernel<<<grid, block, 0, stream>>>(x, Wx, Wh, b, Wd, bd, dropr, out);
}